// Round 3
// baseline (422.575 us; speedup 1.0000x reference)
//
#include <hip/hip_runtime.h>

// ---------------------------------------------------------------------------
// Fused MultiHeadAttention forward for MI355X (gfx950).  Round 8.
//   B=4, S=2048, D_MODEL=1024, H=16, depth=64
// Round-8 changes:
//  - ALL MFMA kernels (gemm_qkv, gemm_wo, attn) moved to the T3-minimum
//    1-barrier double-buffered pipeline: STAGE(next buf) issued at top of
//    iter, compute current buf, single __syncthreads() at end (its implicit
//    vmcnt(0) drain overlaps the whole compute phase).  Round-7 used the
//    fully-exposed sync->STAGE->sync form (m233: ~72% critical path).
//  - attn: denominator now accumulated by an extra ones-MFMA per P-fragment
//    (acc_l = mfma(pa, ones)) -> every lane holds its own rows' sums; the
//    32 lsum adds/iter and the Lsm + shfl epilogue are gone.  Numerator and
//    denominator use the SAME bf16-rounded P (consistency, not a precision
//    loss).
//  - attn: keep-bit mask via 1-op v_bfe_i32 (sbfe) instead of shl/ashr/and.
//  - NO inline asm anywhere (round-6 NaN suspect stays out).
// ---------------------------------------------------------------------------

typedef __bf16 bf16_t;
typedef __bf16 bf16x4 __attribute__((ext_vector_type(4)));
typedef __bf16 bf16x8 __attribute__((ext_vector_type(8)));
typedef float floatx4 __attribute__((ext_vector_type(4)));
typedef float floatx16 __attribute__((ext_vector_type(16)));

#define DMODEL 1024
#define NHEAD  16
#define DEPTH  64
#define BATCH  4
#define SEQ    2048
#define MROWS  (BATCH * SEQ)   // 8192

// exp(s) = exp2(s*log2e); fold log2(e)/8 into Wq (and bq) so QK^T is exp2-ready
#define QSCALE 0.18033688011112042f

#define GLDS16(gaddr, laddr)                                                   \
  __builtin_amdgcn_global_load_lds(                                            \
      (__attribute__((address_space(1))) void*)(gaddr),                        \
      (__attribute__((address_space(3))) void*)(laddr), 16, 0, 0)

// ---------------------------------------------------------------------------
// fp32 -> bf16 for the 4 weight matrices, Wq pre-scaled by QSCALE.
// ---------------------------------------------------------------------------
__global__ __launch_bounds__(256) void cvt_weights(
    const float* __restrict__ w0, const float* __restrict__ w1,
    const float* __restrict__ w2, const float* __restrict__ w3,
    bf16_t* __restrict__ out) {
  const int n_per4 = (DMODEL * DMODEL) / 4;
  int idx = blockIdx.x * blockDim.x + threadIdx.x;
  int t = idx / n_per4;
  int e4 = idx - t * n_per4;
  const float* src = (t == 0) ? w0 : (t == 1) ? w1 : (t == 2) ? w2 : w3;
  const float sc = (t == 0) ? QSCALE : 1.0f;
  float4 v = ((const float4*)src)[e4];
  bf16_t* dst = out + (size_t)t * (DMODEL * DMODEL) + (size_t)e4 * 4;
  dst[0] = (bf16_t)(v.x * sc); dst[1] = (bf16_t)(v.y * sc);
  dst[2] = (bf16_t)(v.z * sc); dst[3] = (bf16_t)(v.w * sc);
}

// ---------------------------------------------------------------------------
// fp32 -> bf16 for the three activation inputs into one 48MB buffer.
// ---------------------------------------------------------------------------
__global__ __launch_bounds__(256) void cvt3(
    const float* __restrict__ q, const float* __restrict__ k,
    const float* __restrict__ v, bf16_t* __restrict__ dst) {
  const size_t n8 = (size_t)MROWS * DMODEL / 8;  // per-tensor 8-elem groups
  size_t i = (size_t)blockIdx.x * blockDim.x + threadIdx.x;  // 3*n8 threads
  int t = (int)(i / n8);
  size_t e = i - (size_t)t * n8;
  const float* src = (t == 0) ? q : (t == 1) ? k : v;
  const float4* s = (const float4*)(src + e * 8);
  float4 f0 = s[0], f1 = s[1];
  bf16x8 o;
  o[0] = (bf16_t)f0.x; o[1] = (bf16_t)f0.y; o[2] = (bf16_t)f0.z; o[3] = (bf16_t)f0.w;
  o[4] = (bf16_t)f1.x; o[5] = (bf16_t)f1.y; o[6] = (bf16_t)f1.z; o[7] = (bf16_t)f1.w;
  *(bf16x8*)(dst + i * 8) = o;
}

// ---------------------------------------------------------------------------
// Mask -> per-lane u32 KEEP-bit words (bit=1 means keep) matched to the
// swapped-QK^T 32x32x16 C layout with permuted-K staging:
//   word[((b*64 + g)*32 + it)*64 + lane]:
//     q  = g*32 + (lane&31),  hi = lane>>5
//     bit (kb*16 + r) = 1 iff
//       m_in[b][q][ it*64 + kb*32 + 16*(r>>3) + 8*hi + 4*((r>>2)&1) + (r&3) ]
//       == 0
// (key = bit2<->bit3 swap of the C-row index (r&3)+8*(r>>2)+4*hi)
// ---------------------------------------------------------------------------
__global__ __launch_bounds__(256) void mask_prepack(
    const float* __restrict__ m, unsigned int* __restrict__ M32) {
  size_t t = (size_t)blockIdx.x * blockDim.x + threadIdx.x;  // 4*64*32*64
  int lane = (int)(t & 63);
  int it = (int)((t >> 6) & 31);
  int g  = (int)((t >> 11) & 63);
  int b  = (int)(t >> 17);
  int q  = g * 32 + (lane & 31);
  int hi = lane >> 5;
  const float* row = m + ((size_t)b * SEQ + q) * SEQ + it * 64;
  unsigned int bits = 0;
#pragma unroll
  for (int kb = 0; kb < 2; kb++) {
#pragma unroll
    for (int rc = 0; rc < 4; rc++) {  // rc = r>>2
      const int base = kb * 32 + 16 * (rc >> 1) + 8 * hi + 4 * (rc & 1);
      const float4 mv = *(const float4*)(row + base);
      const int bit0 = kb * 16 + rc * 4;
      if (mv.x == 0.f) bits |= 1u << (bit0 + 0);
      if (mv.y == 0.f) bits |= 1u << (bit0 + 1);
      if (mv.z == 0.f) bits |= 1u << (bit0 + 2);
      if (mv.w == 0.f) bits |= 1u << (bit0 + 3);
    }
  }
  M32[t] = bits;
}

// ---------------------------------------------------------------------------
// Merged QKV GEMM: z = blockIdx.z selects (input, weight, bias, output).
// 1-barrier double-buffered pipeline, 128x128 tile, BK=32, GLDS16 staging.
// z<2 -> bf16 out [B,H,S,64] (Q,K); z==2 -> bf16 out [B,H,64,S] (V^T).
// ---------------------------------------------------------------------------
__global__ __launch_bounds__(256) void gemm_qkv(
    const bf16_t* __restrict__ Abf3, const bf16_t* __restrict__ Wbf,
    const float* __restrict__ bq, const float* __restrict__ bk,
    const float* __restrict__ bv, bf16_t* __restrict__ Qh,
    bf16_t* __restrict__ Kh, bf16_t* __restrict__ Vth) {
  __shared__ __align__(16) bf16_t As[2][128 * 32];
  __shared__ __align__(16) bf16_t Bs[2][128 * 32];
  const int K = DMODEL;
  const int tid = threadIdx.x;
  const int lane = tid & 63;
  const int w = tid >> 6;
  const int quad = lane >> 4;
  const int l16 = lane & 15;
  const int wm = w & 1, wn = w >> 1;
  const int z = blockIdx.z;

  const bf16_t* A = Abf3 + (size_t)z * MROWS * DMODEL;
  const bf16_t* Bt = Wbf + (size_t)z * DMODEL * DMODEL;
  const float* bias = (z == 0) ? bq : (z == 1) ? bk : bv;
  const float bias_scale = (z == 0) ? QSCALE : 1.0f;
  bf16_t* Ov = (z == 0) ? Qh : (z == 1) ? Kh : Vth;

  const int lin = blockIdx.x + 8 * blockIdx.y;   // (8,64) per z
  const int c = lin & 7;
  const int j = lin >> 3;            // 0..63
  const int n0 = (j & 7) * 128;
  const int m0 = ((j >> 3) * 8 + c) * 128;

  const int r4 = lane >> 2;
  const int c4 = (lane & 3) ^ (r4 & 3);
  const bf16_t* Ag = A + (size_t)(m0 + w * 32 + r4) * K + c4 * 8;
  const bf16_t* Bg = Bt + (size_t)(n0 + w * 32 + r4) * K + c4 * 8;
  const int wslice = (w * 32) * 64;  // byte offset of wave's staging slice

  floatx4 acc[4][4] = {};

#define STAGEG(kkv, buf)                                                       \
  do {                                                                         \
    char* AsB_ = (char*)As[buf] + wslice;                                      \
    char* BsB_ = (char*)Bs[buf] + wslice;                                      \
    GLDS16(Ag + (kkv), AsB_);                                                  \
    GLDS16(Ag + (kkv) + (size_t)16 * K, AsB_ + 16 * 64);                       \
    GLDS16(Bg + (kkv), BsB_);                                                  \
    GLDS16(Bg + (kkv) + (size_t)16 * K, BsB_ + 16 * 64);                       \
  } while (0)

  STAGEG(0, 0);
  __syncthreads();

  const int NIT = K / 32;
  for (int t = 0; t < NIT; ++t) {
    const int cur = t & 1;
    if (t + 1 < NIT) STAGEG((t + 1) * 32, cur ^ 1);

    bf16x8 af[4], bfr[4];
#pragma unroll
    for (int mi = 0; mi < 4; mi++) {
      const char* Arow = (const char*)As[cur] + (wm * 64 + mi * 16 + l16) * 64;
      af[mi] = *(const bf16x8*)(Arow + ((quad ^ (l16 & 3)) * 16));
    }
#pragma unroll
    for (int ni = 0; ni < 4; ni++) {
      const char* Brow = (const char*)Bs[cur] + (wn * 64 + ni * 16 + l16) * 64;
      bfr[ni] = *(const bf16x8*)(Brow + ((quad ^ (l16 & 3)) * 16));
    }
#pragma unroll
    for (int mi = 0; mi < 4; mi++)
#pragma unroll
      for (int ni = 0; ni < 4; ni++)
        acc[mi][ni] = __builtin_amdgcn_mfma_f32_16x16x32_bf16(af[mi], bfr[ni], acc[mi][ni], 0, 0, 0);
    __syncthreads();
  }
#undef STAGEG

#pragma unroll
  for (int ni = 0; ni < 4; ni++) {
    const int col = n0 + wn * 64 + ni * 16 + l16;
    const float bvl = bias_scale * bias[col];
    const int hh = col >> 6, d = col & (DEPTH - 1);
#pragma unroll
    for (int mi = 0; mi < 4; mi++) {
#pragma unroll
      for (int r = 0; r < 4; r++) {
        const int row = m0 + wm * 64 + mi * 16 + quad * 4 + r;
        const float val = acc[mi][ni][r] + bvl;
        const int bb = row >> 11, s = row & (SEQ - 1);
        if (z != 2) {
          Ov[((((size_t)bb * NHEAD + hh) * SEQ + s) << 6) + d] = (bf16_t)val;
        } else {
          Ov[(((size_t)bb * NHEAD + hh) * DEPTH + d) * SEQ + s] = (bf16_t)val;
        }
      }
    }
  }
}

// ---------------------------------------------------------------------------
// Output-projection GEMM (A bf16, fp32 out [M,N]).  1-barrier dbuf pipeline.
// ---------------------------------------------------------------------------
__global__ __launch_bounds__(256) void gemm_wo(
    const bf16_t* __restrict__ A, const bf16_t* __restrict__ Bt,
    const float* __restrict__ bias, float* __restrict__ Ov,
    int M, int N, int K) {
  __shared__ __align__(16) bf16_t As[2][128 * 32];
  __shared__ __align__(16) bf16_t Bs[2][128 * 32];
  const int tid = threadIdx.x;
  const int lane = tid & 63;
  const int w = tid >> 6;
  const int quad = lane >> 4;
  const int l16 = lane & 15;
  const int wm = w & 1, wn = w >> 1;

  const int lin = blockIdx.x + 8 * blockIdx.y;
  const int c = lin & 7;
  const int j = lin >> 3;
  const int n0 = (j & 7) * 128;
  const int m0 = ((j >> 3) * 8 + c) * 128;

  const int r4 = lane >> 2;
  const int c4 = (lane & 3) ^ (r4 & 3);
  const bf16_t* Ag = A + (size_t)(m0 + w * 32 + r4) * K + c4 * 8;
  const bf16_t* Bg = Bt + (size_t)(n0 + w * 32 + r4) * K + c4 * 8;
  const int wslice = (w * 32) * 64;

  floatx4 acc[4][4] = {};

#define STAGEG(kkv, buf)                                                       \
  do {                                                                         \
    char* AsB_ = (char*)As[buf] + wslice;                                      \
    char* BsB_ = (char*)Bs[buf] + wslice;                                      \
    GLDS16(Ag + (kkv), AsB_);                                                  \
    GLDS16(Ag + (kkv) + (size_t)16 * K, AsB_ + 16 * 64);                       \
    GLDS16(Bg + (kkv), BsB_);                                                  \
    GLDS16(Bg + (kkv) + (size_t)16 * K, BsB_ + 16 * 64);                       \
  } while (0)

  STAGEG(0, 0);
  __syncthreads();

  const int NIT = K / 32;
  for (int t = 0; t < NIT; ++t) {
    const int cur = t & 1;
    if (t + 1 < NIT) STAGEG((t + 1) * 32, cur ^ 1);

    bf16x8 af[4], bfr[4];
#pragma unroll
    for (int mi = 0; mi < 4; mi++) {
      const char* Arow = (const char*)As[cur] + (wm * 64 + mi * 16 + l16) * 64;
      af[mi] = *(const bf16x8*)(Arow + ((quad ^ (l16 & 3)) * 16));
    }
#pragma unroll
    for (int ni = 0; ni < 4; ni++) {
      const char* Brow = (const char*)Bs[cur] + (wn * 64 + ni * 16 + l16) * 64;
      bfr[ni] = *(const bf16x8*)(Brow + ((quad ^ (l16 & 3)) * 16));
    }
#pragma unroll
    for (int mi = 0; mi < 4; mi++)
#pragma unroll
      for (int ni = 0; ni < 4; ni++)
        acc[mi][ni] = __builtin_amdgcn_mfma_f32_16x16x32_bf16(af[mi], bfr[ni], acc[mi][ni], 0, 0, 0);
    __syncthreads();
  }
#undef STAGEG

#pragma unroll
  for (int ni = 0; ni < 4; ni++) {
    const int col = n0 + wn * 64 + ni * 16 + l16;
    const float bv = bias[col];
#pragma unroll
    for (int mi = 0; mi < 4; mi++)
#pragma unroll
      for (int r = 0; r < 4; r++) {
        const int row = m0 + wm * 64 + mi * 16 + quad * 4 + r;
        Ov[(size_t)row * N + col] = acc[mi][ni][r] + bv;
      }
  }
}

// ---------------------------------------------------------------------------
// Attention, round 8: swapped QK^T on 32x32x16 MFMA, in-register P,
// 1-barrier double-buffered K/V staging, ones-MFMA denominator.
// 1 block (4 waves) per (b, h, 128 q-rows); wave owns 32 q-rows (q = lane&31).
// ---------------------------------------------------------------------------
__global__ __launch_bounds__(256, 4) void attn_kernel(
    const bf16_t* __restrict__ Qh, const bf16_t* __restrict__ Kh,
    const bf16_t* __restrict__ Vt, const unsigned int* __restrict__ M32,
    bf16_t* __restrict__ O) {
  const int lane = threadIdx.x & 63;
  const int w = __builtin_amdgcn_readfirstlane(threadIdx.x >> 6);
  const int l31 = lane & 31;
  const int hi = lane >> 5;

  const int lin = blockIdx.x + 16 * blockIdx.y + 256 * blockIdx.z;  // 0..1023
  const int x8 = lin & 7;
  const int kk = lin >> 3;
  const int qt = kk & 15;               // q-tile
  const int bh = ((kk >> 4) << 3) | x8; // (b,h) pair
  const int h = bh & 15;
  const int b = bh >> 4;
  const int q0 = qt * 128;

  const bf16_t* Qb = Qh + ((size_t)b * NHEAD + h) * SEQ * DEPTH;
  const bf16_t* Kb = Kh + ((size_t)b * NHEAD + h) * SEQ * DEPTH;
  const bf16_t* Vb = Vt + ((size_t)b * NHEAD + h) * DEPTH * SEQ;
  const unsigned int* Mw =
      M32 + ((size_t)b * 64 + (qt * 4 + w)) * 32 * 64 + lane;

  __shared__ __align__(16) bf16_t Ksm[2][64 * 64];  // [buf][key'][depth], swz
  __shared__ __align__(16) bf16_t Vsm[2][64 * 64];  // [buf][depth][key], swz

  // Staging: LDS dest is linear (wave base + lane*16); global source row is
  // the bit2<->bit3-permuted key (involution); col chunk is XOR-swizzled.
  const int r8 = lane >> 3;
  const int c8 = (lane & 7) ^ r8;
  const int i1 = w * 16 + r8;          // LDS row, first K call
  const int i2 = i1 + 8;               // LDS row, second K call
  const int lo1 = i1 & 31, lo2 = i2 & 31;
  const int s1 = (i1 & 32) | ((lo1 & ~12) | ((lo1 & 4) << 1) | ((lo1 & 8) >> 1));
  const int s2 = (i2 & 32) | ((lo2 & ~12) | ((lo2 & 4) << 1) | ((lo2 & 8) >> 1));
  const bf16_t* Kg1 = Kb + (size_t)s1 * DEPTH + c8 * 8;
  const bf16_t* Kg2 = Kb + (size_t)s2 * DEPTH + c8 * 8;
  const bf16_t* Vg  = Vb + (size_t)(w * 16 + r8) * SEQ + c8 * 8;
  const int woff = (w * 16) * 128;     // byte offset of wave's staging slice

  // Q fragments (B-operand): aq[t] = Q[q][t*16 + hi*8 + j], q = q0+w*32+l31
  bf16x8 aq[4];
  {
    const bf16_t* qp = Qb + (size_t)(q0 + w * 32 + l31) * DEPTH + hi * 8;
#pragma unroll
    for (int t = 0; t < 4; t++) aq[t] = *(const bf16x8*)(qp + t * 16);
  }

  bf16x8 vone;
#pragma unroll
  for (int j2 = 0; j2 < 8; j2++) vone[j2] = (bf16_t)1.0f;

  floatx16 acco[2] = {};
  floatx16 accl = {};
  const int kxor = l31 & 7;

#define STAGE(itv, buf)                                                        \
  do {                                                                         \
    const int sk_ = (itv) * 64;                                                \
    char* KsB_ = (char*)Ksm[buf] + woff;                                       \
    char* VsB_ = (char*)Vsm[buf] + woff;                                       \
    GLDS16(Kg1 + (size_t)sk_ * DEPTH, KsB_);                                   \
    GLDS16(Kg2 + (size_t)sk_ * DEPTH, KsB_ + 8 * 128);                         \
    GLDS16(Vg + sk_, VsB_);                                                    \
    GLDS16(Vg + sk_ + (size_t)8 * SEQ, VsB_ + 8 * 128);                        \
  } while (0)

  STAGE(0, 0);
  __syncthreads();

  const int NT = SEQ / 64;
  for (int it = 0; it < NT; ++it) {
    const int cur = it & 1;
    if (it + 1 < NT) STAGE(it + 1, cur ^ 1);   // overlaps compute below

    const unsigned int mword = Mw[it * 64];
    const char* Kbuf = (const char*)Ksm[cur];
    const char* Vbuf = (const char*)Vsm[cur];

#pragma unroll
    for (int kb = 0; kb < 2; kb++) {
      // ---- QK^T: S^T tile, A = K' (permuted rows), B = Q ----
      floatx16 s = {};
      const char* Krow = Kbuf + (kb * 32 + l31) * 128;
      __builtin_amdgcn_s_setprio(1);
#pragma unroll
      for (int t = 0; t < 4; t++) {
        bf16x8 kf = *(const bf16x8*)(Krow + (((2 * t + hi) ^ kxor) * 16));
        s = __builtin_amdgcn_mfma_f32_32x32x16_bf16(kf, aq[t], s, 0, 0, 0);
      }
      __builtin_amdgcn_s_setprio(0);
      // ---- exp2, keep-bit mask (sbfe); P stays in registers ----
      float pv[16];
#pragma unroll
      for (int r = 0; r < 16; r++) {
        float e = __builtin_amdgcn_exp2f(s[r]);
        const int km = __builtin_amdgcn_sbfe((int)mword, kb * 16 + r, 1);
        pv[r] = __int_as_float(__float_as_int(e) & km);
      }
      // ---- PV + ones-denominator ----
#pragma unroll
      for (int mh = 0; mh < 2; mh++) {
        bf16x8 pa;
#pragma unroll
        for (int j2 = 0; j2 < 8; j2++) pa[j2] = (bf16_t)pv[mh * 8 + j2];
        const int m = kb * 2 + mh;
        __builtin_amdgcn_s_setprio(1);
        accl = __builtin_amdgcn_mfma_f32_32x32x16_bf16(pa, vone, accl, 0, 0, 0);
#pragma unroll
        for (int n = 0; n < 2; n++) {
          const char* Vrow = Vbuf + (n * 32 + l31) * 128;
          bf16x8 vf = *(const bf16x8*)(Vrow + (((2 * m + hi) ^ kxor) * 16));
          acco[n] = __builtin_amdgcn_mfma_f32_32x32x16_bf16(pa, vf, acco[n], 0, 0, 0);
        }
        __builtin_amdgcn_s_setprio(0);
      }
    }
    __syncthreads();   // drains this iter's STAGE; next buf ready
  }
#undef STAGE

  // ---- epilogue: per-lane denominator (from ones-MFMA) and store ----
#pragma unroll
  for (int r = 0; r < 16; r++) {
    const float inv = __frcp_rn(accl[r]);
    const int qr = (r & 3) + 8 * (r >> 2) + 4 * hi;   // true q-row (C layout)
    const size_t srow = (size_t)q0 + w * 32 + qr;
#pragma unroll
    for (int n = 0; n < 2; n++) {
      const int d = h * DEPTH + n * 32 + l31;
      O[((size_t)b * SEQ + srow) * DMODEL + d] = (bf16_t)(acco[n][r] * inv);
    }
  }
}

// ---------------------------------------------------------------------------
extern "C" void kernel_launch(void* const* d_in, const int* in_sizes, int n_in,
                              void* d_out, int out_size, void* d_ws, size_t ws_size,
                              hipStream_t stream) {
  const float* q_in = (const float*)d_in[0];
  const float* k_in = (const float*)d_in[1];
  const float* v_in = (const float*)d_in[2];
  const float* m_in = (const float*)d_in[3];
  const float* Wq = (const float*)d_in[4];
  const float* bq = (const float*)d_in[5];
  const float* Wk = (const float*)d_in[6];
  const float* bk = (const float*)d_in[7];
  const float* Wv = (const float*)d_in[8];
  const float* bv = (const float*)d_in[9];
  const float* Wo = (const float*)d_in[10];
  const float* bo = (const float*)d_in[11];

  // workspace layout:
  //   [0,   8MB) : bf16 weights Wq|Wk|Wv|Wo
  //   [8,  56MB) : Abf3 (3 x 16MB bf16 activations); first 16MB reused as
  //                Obuf after the QKV GEMMs complete (stream-ordered)
  //   [56, 72MB) : Qh  bf16 [B,H,S,64]
  //   [72, 88MB) : Kh  bf16 [B,H,S,64]
  //   [88,104MB) : Vth bf16 [B,H,64,S]
  //   [104,106MB): M32 keep-bit words
  char* ws = (char*)d_ws;
  const size_t MB = 1024 * 1024;
  bf16_t* wbf  = (bf16_t*)ws;
  bf16_t* Abf3 = (bf16_t*)(ws + 8 * MB);
  bf16_t* Obuf = (bf16_t*)(ws + 8 * MB);   // aliases Abf3[0] (safe: QKV done)
  bf16_t* Qh   = (bf16_t*)(ws + 56 * MB);
  bf16_t* Kh   = (bf16_t*)(ws + 72 * MB);
  bf16_t* Vth  = (bf16_t*)(ws + 88 * MB);
  unsigned int* M32 = (unsigned int*)(ws + 104 * MB);

  cvt_weights<<<(4 * (DMODEL * DMODEL / 4)) / 256, 256, 0, stream>>>(
      Wq, Wk, Wv, Wo, wbf);
  cvt3<<<(3 * (MROWS * DMODEL / 8)) / 256, 256, 0, stream>>>(
      q_in, k_in, v_in, Abf3);
  mask_prepack<<<(BATCH * 64 * 32 * 64) / 256, 256, 0, stream>>>(m_in, M32);

  dim3 gqkv(8, 64, 3);
  gemm_qkv<<<gqkv, 256, 0, stream>>>(Abf3, wbf, bq, bk, bv, Qh, Kh, Vth);

  dim3 ga(SEQ / 128, NHEAD, BATCH);  // (16,16,4)
  attn_kernel<<<ga, 256, 0, stream>>>(Qh, Kh, Vth, M32, Obuf);

  dim3 gg(8, 64);
  gemm_wo<<<gg, 256, 0, stream>>>(
      Obuf, wbf + 3 * (size_t)DMODEL * DMODEL, bo, (float*)d_out,
      MROWS, DMODEL, DMODEL);
}

// Round 4
// 405.345 us; speedup vs baseline: 1.0425x; 1.0425x over previous
//
#include <hip/hip_runtime.h>

// ---------------------------------------------------------------------------
// Fused MultiHeadAttention forward for MI355X (gfx950).  Round 9.
//   B=4, S=2048, D_MODEL=1024, H=16, depth=64
// Round-9 changes:
//  - attn reverted to the round-7-measured structure (two-barrier single-buf
//    staging, VALU lsum + Lsm epilogue; NO ones-MFMA, NO setprio — round-8's
//    +10us regression), keeping round-8's sbfe mask; row-sum now paired into
//    float2 (v_pk_add_f32) and mword prefetched at iter top.
//  - gemm_qkv / gemm_wo: BK 32 -> 64 (two-barrier, single 32KB LDS buffer):
//    halves the barrier/drain events per K-loop (32 -> 16), 32 MFMA per
//    stage.  Fragment reads keep the conflict-free 16-row-span XOR pattern.
// ---------------------------------------------------------------------------

typedef __bf16 bf16_t;
typedef __bf16 bf16x4 __attribute__((ext_vector_type(4)));
typedef __bf16 bf16x8 __attribute__((ext_vector_type(8)));
typedef float floatx2 __attribute__((ext_vector_type(2)));
typedef float floatx4 __attribute__((ext_vector_type(4)));
typedef float floatx16 __attribute__((ext_vector_type(16)));

#define DMODEL 1024
#define NHEAD  16
#define DEPTH  64
#define BATCH  4
#define SEQ    2048
#define MROWS  (BATCH * SEQ)   // 8192

// exp(s) = exp2(s*log2e); fold log2(e)/8 into Wq (and bq) so QK^T is exp2-ready
#define QSCALE 0.18033688011112042f

#define GLDS16(gaddr, laddr)                                                   \
  __builtin_amdgcn_global_load_lds(                                            \
      (__attribute__((address_space(1))) void*)(gaddr),                        \
      (__attribute__((address_space(3))) void*)(laddr), 16, 0, 0)

// ---------------------------------------------------------------------------
// fp32 -> bf16 for the 4 weight matrices, Wq pre-scaled by QSCALE.
// ---------------------------------------------------------------------------
__global__ __launch_bounds__(256) void cvt_weights(
    const float* __restrict__ w0, const float* __restrict__ w1,
    const float* __restrict__ w2, const float* __restrict__ w3,
    bf16_t* __restrict__ out) {
  const int n_per4 = (DMODEL * DMODEL) / 4;
  int idx = blockIdx.x * blockDim.x + threadIdx.x;
  int t = idx / n_per4;
  int e4 = idx - t * n_per4;
  const float* src = (t == 0) ? w0 : (t == 1) ? w1 : (t == 2) ? w2 : w3;
  const float sc = (t == 0) ? QSCALE : 1.0f;
  float4 v = ((const float4*)src)[e4];
  bf16_t* dst = out + (size_t)t * (DMODEL * DMODEL) + (size_t)e4 * 4;
  dst[0] = (bf16_t)(v.x * sc); dst[1] = (bf16_t)(v.y * sc);
  dst[2] = (bf16_t)(v.z * sc); dst[3] = (bf16_t)(v.w * sc);
}

// ---------------------------------------------------------------------------
// fp32 -> bf16 for the three activation inputs into one 48MB buffer.
// ---------------------------------------------------------------------------
__global__ __launch_bounds__(256) void cvt3(
    const float* __restrict__ q, const float* __restrict__ k,
    const float* __restrict__ v, bf16_t* __restrict__ dst) {
  const size_t n8 = (size_t)MROWS * DMODEL / 8;  // per-tensor 8-elem groups
  size_t i = (size_t)blockIdx.x * blockDim.x + threadIdx.x;  // 3*n8 threads
  int t = (int)(i / n8);
  size_t e = i - (size_t)t * n8;
  const float* src = (t == 0) ? q : (t == 1) ? k : v;
  const float4* s = (const float4*)(src + e * 8);
  float4 f0 = s[0], f1 = s[1];
  bf16x8 o;
  o[0] = (bf16_t)f0.x; o[1] = (bf16_t)f0.y; o[2] = (bf16_t)f0.z; o[3] = (bf16_t)f0.w;
  o[4] = (bf16_t)f1.x; o[5] = (bf16_t)f1.y; o[6] = (bf16_t)f1.z; o[7] = (bf16_t)f1.w;
  *(bf16x8*)(dst + i * 8) = o;
}

// ---------------------------------------------------------------------------
// Mask -> per-lane u32 KEEP-bit words (bit=1 means keep) matched to the
// swapped-QK^T 32x32x16 C layout with permuted-K staging:
//   word[((b*64 + g)*32 + it)*64 + lane]:
//     q  = g*32 + (lane&31),  hi = lane>>5
//     bit (kb*16 + r) = 1 iff
//       m_in[b][q][ it*64 + kb*32 + 16*(r>>3) + 8*hi + 4*((r>>2)&1) + (r&3) ]
//       == 0
// ---------------------------------------------------------------------------
__global__ __launch_bounds__(256) void mask_prepack(
    const float* __restrict__ m, unsigned int* __restrict__ M32) {
  size_t t = (size_t)blockIdx.x * blockDim.x + threadIdx.x;  // 4*64*32*64
  int lane = (int)(t & 63);
  int it = (int)((t >> 6) & 31);
  int g  = (int)((t >> 11) & 63);
  int b  = (int)(t >> 17);
  int q  = g * 32 + (lane & 31);
  int hi = lane >> 5;
  const float* row = m + ((size_t)b * SEQ + q) * SEQ + it * 64;
  unsigned int bits = 0;
#pragma unroll
  for (int kb = 0; kb < 2; kb++) {
#pragma unroll
    for (int rc = 0; rc < 4; rc++) {  // rc = r>>2
      const int base = kb * 32 + 16 * (rc >> 1) + 8 * hi + 4 * (rc & 1);
      const float4 mv = *(const float4*)(row + base);
      const int bit0 = kb * 16 + rc * 4;
      if (mv.x == 0.f) bits |= 1u << (bit0 + 0);
      if (mv.y == 0.f) bits |= 1u << (bit0 + 1);
      if (mv.z == 0.f) bits |= 1u << (bit0 + 2);
      if (mv.w == 0.f) bits |= 1u << (bit0 + 3);
    }
  }
  M32[t] = bits;
}

// ---------------------------------------------------------------------------
// Merged QKV GEMM, BK=64: z = blockIdx.z selects (input, weight, bias, out).
// 256 thr / 4 waves, 128x128 tile, two-barrier single-buffer staging,
// 8x global_load_lds(16B) per stage, 32 MFMA per stage.
// z<2 -> bf16 out [B,H,S,64] (Q,K); z==2 -> bf16 out [B,H,64,S] (V^T).
// ---------------------------------------------------------------------------
__global__ __launch_bounds__(256) void gemm_qkv(
    const bf16_t* __restrict__ Abf3, const bf16_t* __restrict__ Wbf,
    const float* __restrict__ bq, const float* __restrict__ bk,
    const float* __restrict__ bv, bf16_t* __restrict__ Qh,
    bf16_t* __restrict__ Kh, bf16_t* __restrict__ Vth) {
  __shared__ __align__(16) bf16_t As[128 * 64];   // 16 KB
  __shared__ __align__(16) bf16_t Bs[128 * 64];   // 16 KB
  const int K = DMODEL;
  const int tid = threadIdx.x;
  const int lane = tid & 63;
  const int w = tid >> 6;
  const int quad = lane >> 4;
  const int l16 = lane & 15;
  const int wm = w & 1, wn = w >> 1;
  const int z = blockIdx.z;

  const bf16_t* A = Abf3 + (size_t)z * MROWS * DMODEL;
  const bf16_t* Bt = Wbf + (size_t)z * DMODEL * DMODEL;
  const float* bias = (z == 0) ? bq : (z == 1) ? bk : bv;
  const float bias_scale = (z == 0) ? QSCALE : 1.0f;
  bf16_t* Ov = (z == 0) ? Qh : (z == 1) ? Kh : Vth;

  const int lin = blockIdx.x + 8 * blockIdx.y;   // (8,64) per z
  const int c = lin & 7;
  const int j = lin >> 3;            // 0..63
  const int n0 = (j & 7) * 128;
  const int m0 = ((j >> 3) * 8 + c) * 128;

  // Staging: each GLDS16 call covers 8 rows x 128B; col chunk XOR-swizzled.
  const int r8l = lane >> 3;
  const int c8l = (lane & 7) ^ r8l;
  const bf16_t* Ag = A + (size_t)(m0 + w * 32 + r8l) * K + c8l * 8;
  const bf16_t* Bg = Bt + (size_t)(n0 + w * 32 + r8l) * K + c8l * 8;
  char* AsB = (char*)As + (w * 32) * 128;
  char* BsB = (char*)Bs + (w * 32) * 128;

  floatx4 acc[4][4] = {};

  for (int kk = 0; kk < K; kk += 64) {
    __syncthreads();
#pragma unroll
    for (int cl = 0; cl < 4; cl++) {
      GLDS16(Ag + kk + (size_t)(cl * 8) * K, AsB + cl * 8 * 128);
      GLDS16(Bg + kk + (size_t)(cl * 8) * K, BsB + cl * 8 * 128);
    }
    __syncthreads();

#pragma unroll
    for (int kk2 = 0; kk2 < 2; kk2++) {
      bf16x8 af[4], bfr[4];
#pragma unroll
      for (int mi = 0; mi < 4; mi++) {
        const char* Arow = (const char*)As + (wm * 64 + mi * 16 + l16) * 128;
        af[mi] = *(const bf16x8*)(Arow + (((kk2 * 4 + quad) ^ (l16 & 7)) * 16));
      }
#pragma unroll
      for (int ni = 0; ni < 4; ni++) {
        const char* Brow = (const char*)Bs + (wn * 64 + ni * 16 + l16) * 128;
        bfr[ni] = *(const bf16x8*)(Brow + (((kk2 * 4 + quad) ^ (l16 & 7)) * 16));
      }
#pragma unroll
      for (int mi = 0; mi < 4; mi++)
#pragma unroll
        for (int ni = 0; ni < 4; ni++)
          acc[mi][ni] = __builtin_amdgcn_mfma_f32_16x16x32_bf16(af[mi], bfr[ni], acc[mi][ni], 0, 0, 0);
    }
  }

#pragma unroll
  for (int ni = 0; ni < 4; ni++) {
    const int col = n0 + wn * 64 + ni * 16 + l16;
    const float bvl = bias_scale * bias[col];
    const int hh = col >> 6, d = col & (DEPTH - 1);
#pragma unroll
    for (int mi = 0; mi < 4; mi++) {
#pragma unroll
      for (int r = 0; r < 4; r++) {
        const int row = m0 + wm * 64 + mi * 16 + quad * 4 + r;
        const float val = acc[mi][ni][r] + bvl;
        const int bb = row >> 11, s = row & (SEQ - 1);
        if (z != 2) {
          Ov[((((size_t)bb * NHEAD + hh) * SEQ + s) << 6) + d] = (bf16_t)val;
        } else {
          Ov[(((size_t)bb * NHEAD + hh) * DEPTH + d) * SEQ + s] = (bf16_t)val;
        }
      }
    }
  }
}

// ---------------------------------------------------------------------------
// Output-projection GEMM (A bf16, fp32 out [M,N]), BK=64.  Grid (8,64).
// ---------------------------------------------------------------------------
__global__ __launch_bounds__(256) void gemm_wo(
    const bf16_t* __restrict__ A, const bf16_t* __restrict__ Bt,
    const float* __restrict__ bias, float* __restrict__ Ov,
    int M, int N, int K) {
  __shared__ __align__(16) bf16_t As[128 * 64];
  __shared__ __align__(16) bf16_t Bs[128 * 64];
  const int tid = threadIdx.x;
  const int lane = tid & 63;
  const int w = tid >> 6;
  const int quad = lane >> 4;
  const int l16 = lane & 15;
  const int wm = w & 1, wn = w >> 1;

  const int lin = blockIdx.x + 8 * blockIdx.y;
  const int c = lin & 7;
  const int j = lin >> 3;
  const int n0 = (j & 7) * 128;
  const int m0 = ((j >> 3) * 8 + c) * 128;

  const int r8l = lane >> 3;
  const int c8l = (lane & 7) ^ r8l;
  const bf16_t* Ag = A + (size_t)(m0 + w * 32 + r8l) * K + c8l * 8;
  const bf16_t* Bg = Bt + (size_t)(n0 + w * 32 + r8l) * K + c8l * 8;
  char* AsB = (char*)As + (w * 32) * 128;
  char* BsB = (char*)Bs + (w * 32) * 128;

  floatx4 acc[4][4] = {};

  for (int kk = 0; kk < K; kk += 64) {
    __syncthreads();
#pragma unroll
    for (int cl = 0; cl < 4; cl++) {
      GLDS16(Ag + kk + (size_t)(cl * 8) * K, AsB + cl * 8 * 128);
      GLDS16(Bg + kk + (size_t)(cl * 8) * K, BsB + cl * 8 * 128);
    }
    __syncthreads();

#pragma unroll
    for (int kk2 = 0; kk2 < 2; kk2++) {
      bf16x8 af[4], bfr[4];
#pragma unroll
      for (int mi = 0; mi < 4; mi++) {
        const char* Arow = (const char*)As + (wm * 64 + mi * 16 + l16) * 128;
        af[mi] = *(const bf16x8*)(Arow + (((kk2 * 4 + quad) ^ (l16 & 7)) * 16));
      }
#pragma unroll
      for (int ni = 0; ni < 4; ni++) {
        const char* Brow = (const char*)Bs + (wn * 64 + ni * 16 + l16) * 128;
        bfr[ni] = *(const bf16x8*)(Brow + (((kk2 * 4 + quad) ^ (l16 & 7)) * 16));
      }
#pragma unroll
      for (int mi = 0; mi < 4; mi++)
#pragma unroll
        for (int ni = 0; ni < 4; ni++)
          acc[mi][ni] = __builtin_amdgcn_mfma_f32_16x16x32_bf16(af[mi], bfr[ni], acc[mi][ni], 0, 0, 0);
    }
  }

#pragma unroll
  for (int ni = 0; ni < 4; ni++) {
    const int col = n0 + wn * 64 + ni * 16 + l16;
    const float bv = bias[col];
#pragma unroll
    for (int mi = 0; mi < 4; mi++)
#pragma unroll
      for (int r = 0; r < 4; r++) {
        const int row = m0 + wm * 64 + mi * 16 + quad * 4 + r;
        Ov[(size_t)row * N + col] = acc[mi][ni][r] + bv;
      }
  }
}

// ---------------------------------------------------------------------------
// Attention, round 9 = round-7 structure: swapped QK^T on 32x32x16 MFMA,
// in-register P, single-buffered two-barrier K/V staging, lsum denominator
// (paired float2 adds) + Lsm epilogue.  sbfe keep-bit mask.
// 1 block (4 waves) per (b, h, 128 q-rows); wave owns 32 q-rows (q = lane&31).
// ---------------------------------------------------------------------------
__global__ __launch_bounds__(256, 4) void attn_kernel(
    const bf16_t* __restrict__ Qh, const bf16_t* __restrict__ Kh,
    const bf16_t* __restrict__ Vt, const unsigned int* __restrict__ M32,
    bf16_t* __restrict__ O) {
  const int lane = threadIdx.x & 63;
  const int w = __builtin_amdgcn_readfirstlane(threadIdx.x >> 6);
  const int l31 = lane & 31;
  const int hi = lane >> 5;

  const int lin = blockIdx.x + 16 * blockIdx.y + 256 * blockIdx.z;  // 0..1023
  const int x8 = lin & 7;
  const int kk = lin >> 3;
  const int qt = kk & 15;               // q-tile
  const int bh = ((kk >> 4) << 3) | x8; // (b,h) pair
  const int h = bh & 15;
  const int b = bh >> 4;
  const int q0 = qt * 128;

  const bf16_t* Qb = Qh + ((size_t)b * NHEAD + h) * SEQ * DEPTH;
  const bf16_t* Kb = Kh + ((size_t)b * NHEAD + h) * SEQ * DEPTH;
  const bf16_t* Vb = Vt + ((size_t)b * NHEAD + h) * DEPTH * SEQ;
  const unsigned int* Mw =
      M32 + ((size_t)b * 64 + (qt * 4 + w)) * 32 * 64 + lane;

  __shared__ __align__(16) bf16_t Ksm[64 * 64];   // [key'][depth], swizzled
  __shared__ __align__(16) bf16_t Vsm[64 * 64];   // [depth][key], swizzled
  __shared__ float Lsm[4][32];

  // Staging: LDS dest is linear (wave base + lane*16); global source row is
  // the bit2<->bit3-permuted key (involution); col chunk is XOR-swizzled.
  const int r8 = lane >> 3;
  const int c8 = (lane & 7) ^ r8;
  const int i1 = w * 16 + r8;          // LDS row, first K call
  const int i2 = i1 + 8;               // LDS row, second K call
  const int lo1 = i1 & 31, lo2 = i2 & 31;
  const int s1 = (i1 & 32) | ((lo1 & ~12) | ((lo1 & 4) << 1) | ((lo1 & 8) >> 1));
  const int s2 = (i2 & 32) | ((lo2 & ~12) | ((lo2 & 4) << 1) | ((lo2 & 8) >> 1));
  const bf16_t* Kg1 = Kb + (size_t)s1 * DEPTH + c8 * 8;
  const bf16_t* Kg2 = Kb + (size_t)s2 * DEPTH + c8 * 8;
  const bf16_t* Vg  = Vb + (size_t)(w * 16 + r8) * SEQ + c8 * 8;
  const int woff = (w * 16) * 128;     // byte offset of wave's staging slice

  // Q fragments (B-operand): aq[t] = Q[q][t*16 + hi*8 + j], q = q0+w*32+l31
  bf16x8 aq[4];
  {
    const bf16_t* qp = Qb + (size_t)(q0 + w * 32 + l31) * DEPTH + hi * 8;
#pragma unroll
    for (int t = 0; t < 4; t++) aq[t] = *(const bf16x8*)(qp + t * 16);
  }

  floatx16 acco[2] = {};
  floatx2 l2 = {0.f, 0.f};
  const int kxor = l31 & 7;

  for (int it = 0; it < SEQ / 64; ++it) {
    const int sk = it * 64;
    const unsigned int mword = Mw[it * 64];   // prefetch before barriers
    __syncthreads();   // prior iteration's LDS reads complete
    {
      char* KsB = (char*)Ksm + woff;
      char* VsB = (char*)Vsm + woff;
      GLDS16(Kg1 + (size_t)sk * DEPTH, KsB);
      GLDS16(Kg2 + (size_t)sk * DEPTH, KsB + 8 * 128);
      GLDS16(Vg + sk, VsB);
      GLDS16(Vg + sk + (size_t)8 * SEQ, VsB + 8 * 128);
    }
    __syncthreads();   // vmcnt(0) drain: staged K/V visible

#pragma unroll
    for (int kb = 0; kb < 2; kb++) {
      // ---- QK^T: S^T tile, A = K' (permuted rows), B = Q ----
      floatx16 s = {};
      const char* Krow = (const char*)Ksm + (kb * 32 + l31) * 128;
#pragma unroll
      for (int t = 0; t < 4; t++) {
        bf16x8 kf = *(const bf16x8*)(Krow + (((2 * t + hi) ^ kxor) * 16));
        s = __builtin_amdgcn_mfma_f32_32x32x16_bf16(kf, aq[t], s, 0, 0, 0);
      }
      // ---- exp2, keep-bit mask (sbfe); P stays in registers ----
      float pv[16];
#pragma unroll
      for (int r = 0; r < 16; r++) {
        float e = __builtin_amdgcn_exp2f(s[r]);
        const int km = __builtin_amdgcn_sbfe((int)mword, kb * 16 + r, 1);
        pv[r] = __int_as_float(__float_as_int(e) & km);
      }
      // ---- paired row-sum (v_pk_add_f32) ----
#pragma unroll
      for (int r = 0; r < 8; r++)
        l2 += (floatx2){pv[2 * r], pv[2 * r + 1]};
      // ---- PV: A-frag m (= kb*2+mh) is pv[8*mh .. 8*mh+7] packed ----
#pragma unroll
      for (int mh = 0; mh < 2; mh++) {
        bf16x8 pa;
#pragma unroll
        for (int j2 = 0; j2 < 8; j2++) pa[j2] = (bf16_t)pv[mh * 8 + j2];
        const int m = kb * 2 + mh;
#pragma unroll
        for (int n = 0; n < 2; n++) {
          const char* Vrow = (const char*)Vsm + (n * 32 + l31) * 128;
          bf16x8 vf = *(const bf16x8*)(Vrow + (((2 * m + hi) ^ kxor) * 16));
          acco[n] = __builtin_amdgcn_mfma_f32_32x32x16_bf16(pa, vf, acco[n], 0, 0, 0);
        }
      }
    }
  }

  // ---- epilogue: denominator and store ----
  float lsum = l2.x + l2.y;
  float tot = lsum + __shfl_xor(lsum, 32);
  if (lane < 32) Lsm[w][l31] = __frcp_rn(tot);
  __syncthreads();

#pragma unroll
  for (int r = 0; r < 16; r++) {
    const int qr = (r & 3) + 8 * (r >> 2) + 4 * hi;   // true q-row (C layout)
    const float inv = Lsm[w][qr];
    const size_t srow = (size_t)q0 + w * 32 + qr;
#pragma unroll
    for (int n = 0; n < 2; n++) {
      const int d = h * DEPTH + n * 32 + l31;
      O[((size_t)b * SEQ + srow) * DMODEL + d] = (bf16_t)(acco[n][r] * inv);
    }
  }
}

// ---------------------------------------------------------------------------
extern "C" void kernel_launch(void* const* d_in, const int* in_sizes, int n_in,
                              void* d_out, int out_size, void* d_ws, size_t ws_size,
                              hipStream_t stream) {
  const float* q_in = (const float*)d_in[0];
  const float* k_in = (const float*)d_in[1];
  const float* v_in = (const float*)d_in[2];
  const float* m_in = (const float*)d_in[3];
  const float* Wq = (const float*)d_in[4];
  const float* bq = (const float*)d_in[5];
  const float* Wk = (const float*)d_in[6];
  const float* bk = (const float*)d_in[7];
  const float* Wv = (const float*)d_in[8];
  const float* bv = (const float*)d_in[9];
  const float* Wo = (const float*)d_in[10];
  const float* bo = (const float*)d_in[11];

  // workspace layout:
  //   [0,   8MB) : bf16 weights Wq|Wk|Wv|Wo
  //   [8,  56MB) : Abf3 (3 x 16MB bf16 activations); first 16MB reused as
  //                Obuf after the QKV GEMMs complete (stream-ordered)
  //   [56, 72MB) : Qh  bf16 [B,H,S,64]
  //   [72, 88MB) : Kh  bf16 [B,H,S,64]
  //   [88,104MB) : Vth bf16 [B,H,64,S]
  //   [104,106MB): M32 keep-bit words
  char* ws = (char*)d_ws;
  const size_t MB = 1024 * 1024;
  bf16_t* wbf  = (bf16_t*)ws;
  bf16_t* Abf3 = (bf16_t*)(ws + 8 * MB);
  bf16_t* Obuf = (bf16_t*)(ws + 8 * MB);   // aliases Abf3[0] (safe: QKV done)
  bf16_t* Qh   = (bf16_t*)(ws + 56 * MB);
  bf16_t* Kh   = (bf16_t*)(ws + 72 * MB);
  bf16_t* Vth  = (bf16_t*)(ws + 88 * MB);
  unsigned int* M32 = (unsigned int*)(ws + 104 * MB);

  cvt_weights<<<(4 * (DMODEL * DMODEL / 4)) / 256, 256, 0, stream>>>(
      Wq, Wk, Wv, Wo, wbf);
  cvt3<<<(3 * (MROWS * DMODEL / 8)) / 256, 256, 0, stream>>>(
      q_in, k_in, v_in, Abf3);
  mask_prepack<<<(BATCH * 64 * 32 * 64) / 256, 256, 0, stream>>>(m_in, M32);

  dim3 gqkv(8, 64, 3);
  gemm_qkv<<<gqkv, 256, 0, stream>>>(Abf3, wbf, bq, bk, bv, Qh, Kh, Vth);

  dim3 ga(SEQ / 128, NHEAD, BATCH);  // (16,16,4)
  attn_kernel<<<ga, 256, 0, stream>>>(Qh, Kh, Vth, M32, Obuf);

  dim3 gg(8, 64);
  gemm_wo<<<gg, 256, 0, stream>>>(
      Obuf, wbf + 3 * (size_t)DMODEL * DMODEL, bo, (float*)d_out,
      MROWS, DMODEL, DMODEL);
}